// Round 3
// baseline (1165.248 us; speedup 1.0000x reference)
//
#include <hip/hip_runtime.h>
#include <hip/hip_bf16.h>

#define NN 8192
#define HH 256
#define RR 3

#define BM 64
#define BK 64
#define SPLIT 4
#define KSLICE (NN / SPLIT)          // 2048
#define NT (RR * KSLICE / BK)        // 96 k-iters per block (r folded in)

typedef __attribute__((ext_vector_type(8))) short          bf16x8;
typedef __attribute__((ext_vector_type(4))) float          f32x4;
typedef __attribute__((ext_vector_type(4))) unsigned short u16x4;
typedef __attribute__((ext_vector_type(8))) unsigned short u16x8;

// address-space-explicit pointer types for global_load_lds (Sema-safe)
typedef const __attribute__((address_space(1))) unsigned int gbl_u32;
typedef __attribute__((address_space(3)))       unsigned int lds_u32;

__device__ __forceinline__ unsigned short f2bf(float f) {
    unsigned int u = __builtin_bit_cast(unsigned int, f);
    u += 0x7FFF + ((u >> 16) & 1);   // RNE
    return (unsigned short)(u >> 16);
}

// ---------------------------------------------------------------------------
// Kernel A: xw_t = (x @ W[r])^T, bf16, stored as PRE-SWIZZLED 32KB LDS tile
// images: xwt[r][kt][ tile of 256 crows x 64 k ]; within a tile the bf16 for
// (crow,k) lives at byte  crow*128 + (((k&63)*2) ^ ((crow&7)<<4)).
// A linear global_load_lds copy of a tile then yields the swizzled LDS
// layout directly (rule #21: linear dest + pre-swz source + swz read).
// fp32 accumulate, one rounding.
// ---------------------------------------------------------------------------
__global__ __launch_bounds__(256) void xw_kernel(
    const float* __restrict__ x, const float* __restrict__ W,
    unsigned short* __restrict__ xwt)
{
    const int r  = blockIdx.y;
    const int k0 = blockIdx.x * 16;
    const int c  = threadIdx.x;          // output column = tile "crow"

    __shared__ float xs[16][HH];         // 16 KB

    for (int idx = threadIdx.x; idx < 16 * (HH / 4); idx += 256) {
        const int i  = idx >> 6;
        const int h4 = idx & 63;
        ((f32x4*)xs[i])[h4] = ((const f32x4*)(x + (size_t)(k0 + i) * HH))[h4];
    }
    __syncthreads();

    float acc[16];
#pragma unroll
    for (int i = 0; i < 16; ++i) acc[i] = 0.f;

    const float* Wr = W + (size_t)r * HH * HH;
    for (int h = 0; h < HH; h += 8) {
        float w0 = Wr[(h + 0) * HH + c];
        float w1 = Wr[(h + 1) * HH + c];
        float w2 = Wr[(h + 2) * HH + c];
        float w3 = Wr[(h + 3) * HH + c];
        float w4 = Wr[(h + 4) * HH + c];
        float w5 = Wr[(h + 5) * HH + c];
        float w6 = Wr[(h + 6) * HH + c];
        float w7 = Wr[(h + 7) * HH + c];
#pragma unroll
        for (int i = 0; i < 16; ++i) {
            const f32x4 a = *(const f32x4*)&xs[i][h];
            const f32x4 b = *(const f32x4*)&xs[i][h + 4];
            acc[i] += a.x * w0 + a.y * w1 + a.z * w2 + a.w * w3
                    + b.x * w4 + b.y * w5 + b.z * w6 + b.w * w7;
        }
    }

    u16x8 lo, hi;
#pragma unroll
    for (int i = 0; i < 8; ++i) { lo[i] = f2bf(acc[i]); hi[i] = f2bf(acc[i + 8]); }

    const int  kt   = k0 >> 6;                 // 32KB tile index
    const int  ks0b = (k0 & 63) * 2;           // first-k byte within tile row
    const int  s    = (c & 7) << 4;
    char* tb = (char*)xwt + (((size_t)r * 128 + kt) << 15) + c * 128;
    *(u16x8*)(tb + (ks0b ^ s))        = lo;    // k0..k0+7
    *(u16x8*)(tb + ((ks0b + 16) ^ s)) = hi;    // k0+8..k0+15
}

// ---------------------------------------------------------------------------
// Kernel B: split-K partials. Block = 64 rows x 256 cols, 256 thr (4 waves,
// wave tile 64x64 along n). Loops (r, k) so adjs is read exactly once and
// only SPLIT=4 partials/element exist; partials stored with plain dwords.
// 2-phase pipeline (T3-lite): issue next-tile loads first, one barrier/tile.
// A: fp32->bf16 reg-staged, XOR-swizzled LDS. B: global_load_lds of
// pre-swizzled tiles (zero staging VALU).
// ---------------------------------------------------------------------------
__global__ __launch_bounds__(256, 2) void rgcn_spmm(
    const float* __restrict__ adjs, const unsigned short* __restrict__ xwt,
    float* __restrict__ part)
{
    __shared__ unsigned short As[2][BM * BK];   // 2 x  8 KB
    __shared__ unsigned short Bs[2][HH * BK];   // 2 x 32 KB   (total 80 KB)

    // XCD-grouped bijective swizzle (512 = 8 * 64): one XCD works one k-slice
    // region so its 3MB xw_t slice set stays L2-resident.
    const int id    = blockIdx.x;
    const int swz   = (id & 7) * 64 + (id >> 3);
    const int slice = swz >> 7;        // 0..3
    const int mtile = swz & 127;       // 0..127
    const int m0    = mtile * BM;
    const int k0    = slice * KSLICE;

    const int tid  = threadIdx.x;
    const int lane = tid & 63;
    const int wn   = tid >> 6;         // wave 0..3 -> n-quadrant

    f32x4 acc[4][4];
#pragma unroll
    for (int m = 0; m < 4; ++m)
#pragma unroll
        for (int n = 0; n < 4; ++n) acc[m][n] = (f32x4){0.f, 0.f, 0.f, 0.f};

    // --- staging helpers (all compile-time indexed) ---
    auto a_issue = [&](int t, f32x4* areg) {        // 4x global b128 -> regs
        const int r  = t >> 5;
        const int kb = k0 + ((t & 31) << 6);
        const float* A = adjs + (size_t)r * NN * NN + (size_t)m0 * NN + kb;
#pragma unroll
        for (int p = 0; p < 4; ++p) {
            const int idx  = p * 256 + tid;
            const int row  = idx >> 4;
            const int col4 = idx & 15;
            areg[p] = *(const f32x4*)(A + (size_t)row * NN + col4 * 4);
        }
    };
    auto b_issue = [&](int t, int buf) {            // 8x global_load_lds x16B
        const int r  = t >> 5;
        const int kt = (k0 >> 6) + (t & 31);
        const char* src = (const char*)xwt + (((size_t)r * 128 + kt) << 15);
        char* dst = (char*)Bs[buf];
#pragma unroll
        for (int j = 0; j < 8; ++j) {
            const int off = (j * 4 + wn) * 1024;    // wave-uniform LDS base
            __builtin_amdgcn_global_load_lds(
                (gbl_u32*)(src + off + lane * 16),
                (lds_u32*)(dst + off), 16, 0, 0);
        }
    };
    auto a_commit = [&](const f32x4* areg, int buf) {  // cvt + swizzled write
        char* dst = (char*)As[buf];
#pragma unroll
        for (int p = 0; p < 4; ++p) {
            const int idx  = p * 256 + tid;
            const int row  = idx >> 4;
            const int col4 = idx & 15;
            u16x4 b4;
            b4.x = f2bf(areg[p].x); b4.y = f2bf(areg[p].y);
            b4.z = f2bf(areg[p].z); b4.w = f2bf(areg[p].w);
            const int byte = (col4 * 8) ^ ((row & 7) << 4);
            *(u16x4*)(dst + row * 128 + byte) = b4;
        }
    };
    auto compute = [&](int buf) {
#pragma unroll
        for (int ks = 0; ks < 2; ++ks) {
            bf16x8 af[4], bfr[4];
            const int colb = ks * 64 + (lane >> 4) * 16;   // byte offset
#pragma unroll
            for (int m = 0; m < 4; ++m) {
                const int row = m * 16 + (lane & 15);
                af[m] = *(const bf16x8*)((const char*)As[buf] + row * 128
                         + (colb ^ ((row & 7) << 4)));
            }
#pragma unroll
            for (int n = 0; n < 4; ++n) {
                const int crow = wn * 64 + n * 16 + (lane & 15);
                bfr[n] = *(const bf16x8*)((const char*)Bs[buf] + crow * 128
                         + (colb ^ ((crow & 7) << 4)));
            }
#pragma unroll
            for (int m = 0; m < 4; ++m)
#pragma unroll
                for (int n = 0; n < 4; ++n)
                    acc[m][n] = __builtin_amdgcn_mfma_f32_16x16x32_bf16(
                        af[m], bfr[n], acc[m][n], 0, 0, 0);
        }
    };

    // --- prologue: stage tile 0 into buf 0 ---
    {
        f32x4 areg[4];
        a_issue(0, areg);
        b_issue(0, 0);
        a_commit(areg, 0);
    }
    __syncthreads();

    int cur = 0;
    for (int t = 0; t < NT - 1; ++t) {
        f32x4 areg[4];
        a_issue(t + 1, areg);        // HBM loads in flight during compute
        b_issue(t + 1, cur ^ 1);     // L2 loads -> LDS, in flight too
        compute(cur);
        a_commit(areg, cur ^ 1);     // waits only A's vmcnt, then ds_write
        __syncthreads();             // drains vmcnt/lgkm -> next tile ready
        cur ^= 1;
    }
    compute(cur);                    // last tile, no prefetch

    // --- epilogue: plain stores of this block's partial (no atomics) ---
    float* dst = part + (size_t)slice * NN * HH;
#pragma unroll
    for (int m = 0; m < 4; ++m) {
        const int rowb = m0 + m * 16 + (lane >> 4) * 4;
#pragma unroll
        for (int n = 0; n < 4; ++n) {
            const int colb = wn * 64 + n * 16 + (lane & 15);
#pragma unroll
            for (int j = 0; j < 4; ++j)
                dst[(size_t)(rowb + j) * HH + colb] = acc[m][n][j];
        }
    }
}

// ---------------------------------------------------------------------------
// Kernel C: out = sum of 4 partials (reads 32MB, writes 8MB, ~8us)
// ---------------------------------------------------------------------------
__global__ __launch_bounds__(256) void reduce_kernel(
    const float* __restrict__ part, float* __restrict__ out)
{
    const size_t S  = (size_t)NN * HH / 4;         // f32x4 count per slice
    const size_t i  = (size_t)blockIdx.x * 256 + threadIdx.x;
    const f32x4* p  = (const f32x4*)part;
    f32x4 v = p[i] + p[i + S] + p[i + 2 * S] + p[i + 3 * S];
    ((f32x4*)out)[i] = v;
}

extern "C" void kernel_launch(void* const* d_in, const int* in_sizes, int n_in,
                              void* d_out, int out_size, void* d_ws, size_t ws_size,
                              hipStream_t stream)
{
    const float* x    = (const float*)d_in[0];
    const float* adjs = (const float*)d_in[1];
    const float* W    = (const float*)d_in[2];
    float* out = (float*)d_out;

    unsigned short* xwt = (unsigned short*)d_ws;                    // 12 MB
    float* part = (float*)((char*)d_ws + ((size_t)RR * 128 << 15)); // 32 MB

    dim3 gA(NN / 16, RR);
    xw_kernel<<<gA, 256, 0, stream>>>(x, W, xwt);

    rgcn_spmm<<<NN / BM * SPLIT, 256, 0, stream>>>(adjs, xwt, part);

    reduce_kernel<<<(NN * HH / 4) / 256, 256, 0, stream>>>(part, out);
}